// Round 2
// baseline (509.080 us; speedup 1.0000x reference)
//
#include <hip/hip_runtime.h>
#include <math.h>

typedef __bf16 bf16x8v __attribute__((ext_vector_type(8)));
typedef float f32x4 __attribute__((ext_vector_type(4)));

__device__ __forceinline__ void async_copy16(void* lds, const void* g) {
  __builtin_amdgcn_global_load_lds(
      (const __attribute__((address_space(1))) void*)g,
      (__attribute__((address_space(3))) void*)lds, 16, 0, 0);
}

// ---- f32 -> bf16 cast, all 7 tensors in one launch ----
struct CastArgs {
  const float* s[7];
  __bf16* d[7];
};
__global__ __launch_bounds__(256) void cast_kernel(CastArgs a) {
  const int t = blockIdx.y;
  const int n = (t < 3) ? 8388608 : 1048576;
  const int i = (blockIdx.x * 256 + threadIdx.x) * 8;
  if (i >= n) return;
  const float4 v0 = *(const float4*)(a.s[t] + i);
  const float4 v1 = *(const float4*)(a.s[t] + i + 4);
  bf16x8v o;
  o[0] = (__bf16)v0.x; o[1] = (__bf16)v0.y; o[2] = (__bf16)v0.z; o[3] = (__bf16)v0.w;
  o[4] = (__bf16)v1.x; o[5] = (__bf16)v1.y; o[6] = (__bf16)v1.z; o[7] = (__bf16)v1.w;
  *(bf16x8v*)(a.d[t] + i) = o;
}

// C[m,n] = sum_k A[m,k] * B[n,k]   (A: MxK row-major, B: NxK row-major, bf16)
// MODE 0: C[row*N+col] (OutT = float, final output)
// MODE 1: split heads -> [B,H,S,dk]  (row=b*2048+s, col=h*64+d)
// MODE 2: split heads transposed -> [B,H,dk,S]
template <int MODE, typename OutT>
__global__ __launch_bounds__(256) void gemm_bt(const __bf16* __restrict__ A,
                                               const __bf16* __restrict__ B,
                                               OutT* __restrict__ C,
                                               int M, int N, int K) {
  __shared__ __bf16 As[128 * 64];
  __shared__ __bf16 Bs[128 * 64];
  const int tid = threadIdx.x;
  const int wave = tid >> 6, lane = tid & 63;
  const int lgrp = lane >> 4, lmod = lane & 15;
  const int bm = blockIdx.y * 128, bn = blockIdx.x * 128;
  const int wm = (wave >> 1) * 64, wn = (wave & 1) * 64;

  f32x4 acc[4][4];
#pragma unroll
  for (int mi = 0; mi < 4; mi++)
#pragma unroll
    for (int ni = 0; ni < 4; ni++)
#pragma unroll
      for (int r = 0; r < 4; r++) acc[mi][ni][r] = 0.f;

  for (int kt = 0; kt < K; kt += 64) {
#pragma unroll
    for (int i = 0; i < 4; i++) {
      const int eo = i * 2048 + tid * 8;  // element offset in 128x64 tile
      const int r = eo >> 6, c = eo & 63;
      async_copy16(&As[eo], &A[(size_t)(bm + r) * K + kt + c]);
      async_copy16(&Bs[eo], &B[(size_t)(bn + r) * K + kt + c]);
    }
    __syncthreads();
#pragma unroll
    for (int ks = 0; ks < 2; ks++) {
      bf16x8v af[4], bf[4];
#pragma unroll
      for (int mi = 0; mi < 4; mi++)
        af[mi] = *(const bf16x8v*)&As[(wm + mi * 16 + lmod) * 64 + ks * 32 + lgrp * 8];
#pragma unroll
      for (int ni = 0; ni < 4; ni++)
        bf[ni] = *(const bf16x8v*)&Bs[(wn + ni * 16 + lmod) * 64 + ks * 32 + lgrp * 8];
#pragma unroll
      for (int mi = 0; mi < 4; mi++)
#pragma unroll
        for (int ni = 0; ni < 4; ni++)
          acc[mi][ni] = __builtin_amdgcn_mfma_f32_16x16x32_bf16(af[mi], bf[ni],
                                                                acc[mi][ni], 0, 0, 0);
    }
    __syncthreads();
  }

#pragma unroll
  for (int mi = 0; mi < 4; mi++)
#pragma unroll
    for (int ni = 0; ni < 4; ni++)
#pragma unroll
      for (int r = 0; r < 4; r++) {
        const int row = bm + wm + mi * 16 + lgrp * 4 + r;
        const int col = bn + wn + ni * 16 + lmod;
        if (MODE == 0) {
          C[(size_t)row * N + col] = (OutT)acc[mi][ni][r];
        } else if (MODE == 1) {
          C[(size_t)(row >> 11) * 2097152 + (size_t)(col >> 6) * 131072 +
            (size_t)(row & 2047) * 64 + (col & 63)] = (OutT)acc[mi][ni][r];
        } else {
          C[(size_t)(row >> 11) * 2097152 + (size_t)(col >> 6) * 131072 +
            (size_t)(col & 63) * 2048 + (row & 2047)] = (OutT)acc[mi][ni][r];
        }
      }
}

// Flash attention. Qh,Kh: [B,H,S,dk]; Vt: [B,H,dk,S]; O: [B,S,H*dk]  (all bf16)
// grid: (16 q-tiles, 64 b*h), block 256 (4 waves x 32 q-rows)
__global__ __launch_bounds__(256) void attn_kernel(const __bf16* __restrict__ Qh,
                                                   const __bf16* __restrict__ Kh,
                                                   const __bf16* __restrict__ Vt,
                                                   __bf16* __restrict__ O) {
  __shared__ __bf16 Ks[128 * 64];   // [kv][d]
  __shared__ __bf16 Vts[64 * 128];  // [d][kv]
  __shared__ __bf16 Ps[128 * 128];  // [q][kv], per-wave private rows

  const int tid = threadIdx.x;
  const int wave = tid >> 6, lane = tid & 63;
  const int lgrp = lane >> 4, lmod = lane & 15;
  const int qt = blockIdx.x, y = blockIdx.y;  // y = b*16+h
  const size_t hb = (size_t)y * 131072;
  const __bf16* Qb = Qh + hb + (size_t)qt * 128 * 64;
  const __bf16* Kb = Kh + hb;
  const __bf16* Vb = Vt + hb;
  const int wq0 = wave * 32;

  // Q fragments, pre-scaled by 1/sqrt(dk)=0.125 (exact in bf16)
  bf16x8v qf[2][2];
#pragma unroll
  for (int mi = 0; mi < 2; mi++)
#pragma unroll
    for (int ks = 0; ks < 2; ks++) {
      bf16x8v q = *(const bf16x8v*)&Qb[(wq0 + mi * 16 + lmod) * 64 + ks * 32 + lgrp * 8];
#pragma unroll
      for (int j = 0; j < 8; j++) q[j] = (__bf16)((float)q[j] * 0.125f);
      qf[mi][ks] = q;
    }

  float m_run[2][4], l_run[2][4];
  f32x4 oacc[2][4];
#pragma unroll
  for (int mi = 0; mi < 2; mi++)
#pragma unroll
    for (int r = 0; r < 4; r++) {
      m_run[mi][r] = -INFINITY;
      l_run[mi][r] = 0.f;
    }
#pragma unroll
  for (int mi = 0; mi < 2; mi++)
#pragma unroll
    for (int nd = 0; nd < 4; nd++)
#pragma unroll
      for (int r = 0; r < 4; r++) oacc[mi][nd][r] = 0.f;

  for (int kv0 = 0; kv0 < 2048; kv0 += 128) {
#pragma unroll
    for (int i = 0; i < 4; i++) {
      const int eo = i * 2048 + tid * 8;
      async_copy16(&Ks[eo], &Kb[(size_t)kv0 * 64 + eo]);  // contiguous 16KB block
      const int r = eo >> 7, c = eo & 127;
      async_copy16(&Vts[eo], &Vb[(size_t)r * 2048 + kv0 + c]);
    }
    __syncthreads();

    // S = Q K^T  (per wave: 2x8 tiles of 16x16)
    f32x4 s[2][8];
#pragma unroll
    for (int mi = 0; mi < 2; mi++)
#pragma unroll
      for (int ni = 0; ni < 8; ni++)
#pragma unroll
        for (int r = 0; r < 4; r++) s[mi][ni][r] = 0.f;
#pragma unroll
    for (int ks = 0; ks < 2; ks++) {
      bf16x8v kf[8];
#pragma unroll
      for (int ni = 0; ni < 8; ni++)
        kf[ni] = *(const bf16x8v*)&Ks[(ni * 16 + lmod) * 64 + ks * 32 + lgrp * 8];
#pragma unroll
      for (int mi = 0; mi < 2; mi++)
#pragma unroll
        for (int ni = 0; ni < 8; ni++)
          s[mi][ni] = __builtin_amdgcn_mfma_f32_16x16x32_bf16(qf[mi][ks], kf[ni],
                                                              s[mi][ni], 0, 0, 0);
    }

    // online softmax (row = lgrp*4 + r within each 16-tile; 16 cols live in the
    // 16 lanes sharing lgrp -> reduce with xor masks 1,2,4,8)
#pragma unroll
    for (int mi = 0; mi < 2; mi++)
#pragma unroll
      for (int r = 0; r < 4; r++) {
        float rmax = s[mi][0][r];
#pragma unroll
        for (int ni = 1; ni < 8; ni++) rmax = fmaxf(rmax, s[mi][ni][r]);
#pragma unroll
        for (int msk = 1; msk < 16; msk <<= 1) rmax = fmaxf(rmax, __shfl_xor(rmax, msk));
        const float mold = m_run[mi][r];
        const float mnew = fmaxf(mold, rmax);
        const float alpha = __expf(mold - mnew);
        float psum = 0.f;
#pragma unroll
        for (int ni = 0; ni < 8; ni++) {
          const float p = __expf(s[mi][ni][r] - mnew);
          psum += p;
          Ps[(wq0 + mi * 16 + lgrp * 4 + r) * 128 + ni * 16 + lmod] = (__bf16)p;
        }
#pragma unroll
        for (int msk = 1; msk < 16; msk <<= 1) psum += __shfl_xor(psum, msk);
        l_run[mi][r] = l_run[mi][r] * alpha + psum;
        m_run[mi][r] = mnew;
#pragma unroll
        for (int nd = 0; nd < 4; nd++) oacc[mi][nd][r] *= alpha;
      }

    // O += P V   (P rows are wave-private: no barrier needed between write & read)
#pragma unroll
    for (int ks = 0; ks < 4; ks++) {
      bf16x8v pf[2], vf[4];
#pragma unroll
      for (int mi = 0; mi < 2; mi++)
        pf[mi] = *(const bf16x8v*)&Ps[(wq0 + mi * 16 + lmod) * 128 + ks * 32 + lgrp * 8];
#pragma unroll
      for (int nd = 0; nd < 4; nd++)
        vf[nd] = *(const bf16x8v*)&Vts[(nd * 16 + lmod) * 128 + ks * 32 + lgrp * 8];
#pragma unroll
      for (int mi = 0; mi < 2; mi++)
#pragma unroll
        for (int nd = 0; nd < 4; nd++)
          oacc[mi][nd] = __builtin_amdgcn_mfma_f32_16x16x32_bf16(pf[mi], vf[nd],
                                                                 oacc[mi][nd], 0, 0, 0);
    }
    __syncthreads();  // protect Ks/Vts before next stage
  }

  const int b = y >> 4, h = y & 15;
#pragma unroll
  for (int mi = 0; mi < 2; mi++)
#pragma unroll
    for (int r = 0; r < 4; r++) {
      const float inv = 1.f / l_run[mi][r];
      const int srow = qt * 128 + wq0 + mi * 16 + lgrp * 4 + r;
      const size_t base = ((size_t)(b * 2048 + srow)) * 1024 + h * 64;
#pragma unroll
      for (int nd = 0; nd < 4; nd++)
        O[base + nd * 16 + lmod] = (__bf16)(oacc[mi][nd][r] * inv);
    }
}

extern "C" void kernel_launch(void* const* d_in, const int* in_sizes, int n_in,
                              void* d_out, int out_size, void* d_ws, size_t ws_size,
                              hipStream_t stream) {
  const float* Qin = (const float*)d_in[0];
  const float* Kin = (const float*)d_in[1];
  const float* Vin = (const float*)d_in[2];
  const float* Wq = (const float*)d_in[3];
  const float* Wk = (const float*)d_in[4];
  const float* Wv = (const float*)d_in[5];
  const float* Wo = (const float*)d_in[6];
  float* out = (float*)d_out;

  __bf16* base = (__bf16*)d_ws;
  __bf16* Qbf = base;                    // 8388608
  __bf16* Kbf = base + 8388608;
  __bf16* Vbf = base + 16777216;
  __bf16* Wqb = base + 25165824;         // 1048576 each
  __bf16* Wkb = base + 26214400;
  __bf16* Wvb = base + 27262976;
  __bf16* Wob = base + 28311552;
  __bf16* Qh = base + 29360128;          // [B,H,S,dk]
  __bf16* Kh = base + 37748736;          // [B,H,S,dk]
  __bf16* Vt = base + 46137344;          // [B,H,dk,S]
  __bf16* AO = Qbf;                      // aliases Qbf (dead after gemm1)

  CastArgs ca;
  ca.s[0] = Qin; ca.s[1] = Kin; ca.s[2] = Vin;
  ca.s[3] = Wq;  ca.s[4] = Wk;  ca.s[5] = Wv;  ca.s[6] = Wo;
  ca.d[0] = Qbf; ca.d[1] = Kbf; ca.d[2] = Vbf;
  ca.d[3] = Wqb; ca.d[4] = Wkb; ca.d[5] = Wvb; ca.d[6] = Wob;
  cast_kernel<<<dim3(4096, 7), 256, 0, stream>>>(ca);

  const int M = 8192, N = 1024, K = 1024;
  dim3 gg(N / 128, M / 128), bb(256);
  gemm_bt<1, __bf16><<<gg, bb, 0, stream>>>(Qbf, Wqb, Qh, M, N, K);
  gemm_bt<1, __bf16><<<gg, bb, 0, stream>>>(Kbf, Wkb, Kh, M, N, K);
  gemm_bt<2, __bf16><<<gg, bb, 0, stream>>>(Vbf, Wvb, Vt, M, N, K);
  attn_kernel<<<dim3(16, 64), bb, 0, stream>>>(Qh, Kh, Vt, AO);
  gemm_bt<0, float><<<gg, bb, 0, stream>>>(AO, Wob, out, M, N, K);
}

// Round 3
// 429.737 us; speedup vs baseline: 1.1846x; 1.1846x over previous
//
#include <hip/hip_runtime.h>
#include <math.h>

typedef __bf16 bf16x8v __attribute__((ext_vector_type(8)));
typedef float f32x4 __attribute__((ext_vector_type(4)));

__device__ __forceinline__ void async_copy16(void* lds, const void* g) {
  __builtin_amdgcn_global_load_lds(
      (const __attribute__((address_space(1))) void*)g,
      (__attribute__((address_space(3))) void*)lds, 16, 0, 0);
}

// ---- f32 -> bf16 cast, all 7 tensors in one launch ----
struct CastArgs {
  const float* s[7];
  __bf16* d[7];
};
__global__ __launch_bounds__(256) void cast_kernel(CastArgs a) {
  const int t = blockIdx.y;
  const int n = (t < 3) ? 8388608 : 1048576;
  const int i = (blockIdx.x * 256 + threadIdx.x) * 8;
  if (i >= n) return;
  const float4 v0 = *(const float4*)(a.s[t] + i);
  const float4 v1 = *(const float4*)(a.s[t] + i + 4);
  bf16x8v o;
  o[0] = (__bf16)v0.x; o[1] = (__bf16)v0.y; o[2] = (__bf16)v0.z; o[3] = (__bf16)v0.w;
  o[4] = (__bf16)v1.x; o[5] = (__bf16)v1.y; o[6] = (__bf16)v1.z; o[7] = (__bf16)v1.w;
  *(bf16x8v*)(a.d[t] + i) = o;
}

// C[m,n] = sum_k A[m,k] * B[n,k]   (A: MxK row-major, B: NxK row-major, bf16)
// LDS tiles XOR-swizzled at 16B-block granularity: logical block (r,cb) lives
// at LDS block (r, cb^(r&7)) -- staged by permuting the GLOBAL fetch address
// (LDS side of global_load_lds must stay lane-contiguous). Reads XOR back.
// MODE 0: C[row*N+col] (float, final output)
// MODE 1: split heads -> [B,H,S,dk]  (row=b*2048+s, col=h*64+d)
// MODE 3: V^T heads -> [B,H,dk,S]    (row=h*64+d [M=1024], col=b*2048+s [N=8192])
template <int MODE, typename OutT>
__global__ __launch_bounds__(256) void gemm_bt(const __bf16* __restrict__ A,
                                               const __bf16* __restrict__ B,
                                               OutT* __restrict__ C,
                                               int M, int N, int K) {
  __shared__ __bf16 As[128 * 64];
  __shared__ __bf16 Bs[128 * 64];
  const int tid = threadIdx.x;
  const int wave = tid >> 6, lane = tid & 63;
  const int lgrp = lane >> 4, lmod = lane & 15;
  const int bm = blockIdx.y * 128, bn = blockIdx.x * 128;
  const int wm = (wave >> 1) * 64, wn = (wave & 1) * 64;

  f32x4 acc[4][4];
#pragma unroll
  for (int mi = 0; mi < 4; mi++)
#pragma unroll
    for (int ni = 0; ni < 4; ni++)
#pragma unroll
      for (int r = 0; r < 4; r++) acc[mi][ni][r] = 0.f;

  for (int kt = 0; kt < K; kt += 64) {
#pragma unroll
    for (int i = 0; i < 4; i++) {
      const int s = i * 256 + tid;      // 16B-block slot in 128x8-block tile
      const int r = s >> 3, cb = s & 7;
      const int gc = (cb ^ (r & 7)) * 8;  // swizzled global column (elements)
      async_copy16(&As[s * 8], &A[(size_t)(bm + r) * K + kt + gc]);
      async_copy16(&Bs[s * 8], &B[(size_t)(bn + r) * K + kt + gc]);
    }
    __syncthreads();
#pragma unroll
    for (int ks = 0; ks < 2; ks++) {
      bf16x8v af[4], bf[4];
#pragma unroll
      for (int mi = 0; mi < 4; mi++) {
        const int row = wm + mi * 16 + lmod;
        af[mi] = *(const bf16x8v*)&As[row * 64 + ((ks * 4 + lgrp) ^ (row & 7)) * 8];
      }
#pragma unroll
      for (int ni = 0; ni < 4; ni++) {
        const int row = wn + ni * 16 + lmod;
        bf[ni] = *(const bf16x8v*)&Bs[row * 64 + ((ks * 4 + lgrp) ^ (row & 7)) * 8];
      }
#pragma unroll
      for (int mi = 0; mi < 4; mi++)
#pragma unroll
        for (int ni = 0; ni < 4; ni++)
          acc[mi][ni] = __builtin_amdgcn_mfma_f32_16x16x32_bf16(af[mi], bf[ni],
                                                                acc[mi][ni], 0, 0, 0);
    }
    __syncthreads();
  }

#pragma unroll
  for (int mi = 0; mi < 4; mi++)
#pragma unroll
    for (int ni = 0; ni < 4; ni++)
#pragma unroll
      for (int r = 0; r < 4; r++) {
        const int row = bm + wm + mi * 16 + lgrp * 4 + r;
        const int col = bn + wn + ni * 16 + lmod;
        if (MODE == 0) {
          C[(size_t)row * N + col] = (OutT)acc[mi][ni][r];
        } else if (MODE == 1) {
          C[(size_t)(row >> 11) * 2097152 + (size_t)(col >> 6) * 131072 +
            (size_t)(row & 2047) * 64 + (col & 63)] = (OutT)acc[mi][ni][r];
        } else {  // MODE 3: Vt[b][h][d][s], row=h*64+d, col=b*2048+s (coalesced in s)
          C[(size_t)(col >> 11) * 2097152 + (size_t)(row >> 6) * 131072 +
            (size_t)(row & 63) * 2048 + (col & 2047)] = (OutT)acc[mi][ni][r];
        }
      }
}

// Flash attention. Qh,Kh: [B,H,S,dk]; Vt: [B,H,dk,S]; O: [B,S,H*dk]  (all bf16)
// grid: (16 q-tiles, 64 b*h), block 256 (4 waves x 32 q-rows)
// Softmax runs in log2 domain (Q pre-scaled by 0.125*log2e).
__global__ __launch_bounds__(256) void attn_kernel(const __bf16* __restrict__ Qh,
                                                   const __bf16* __restrict__ Kh,
                                                   const __bf16* __restrict__ Vt,
                                                   __bf16* __restrict__ O) {
  __shared__ __bf16 Ks[128 * 64];    // [kv][d], XOR-swizzled 16B blocks
  __shared__ __bf16 Vts[64 * 128];   // [d][kv], XOR-swizzled 16B blocks
  __shared__ __bf16 Ps[128 * 136];   // [q][kv], +8 pad (272B stride, 16B-aligned)

  const int tid = threadIdx.x;
  const int wave = tid >> 6, lane = tid & 63;
  const int lgrp = lane >> 4, lmod = lane & 15;
  const int qt = blockIdx.x, y = blockIdx.y;  // y = b*16+h
  const size_t hb = (size_t)y * 131072;
  const __bf16* Qb = Qh + hb + (size_t)qt * 128 * 64;
  const __bf16* Kb = Kh + hb;
  const __bf16* Vb = Vt + hb;
  const int wq0 = wave * 32;

  // Q fragments, pre-scaled by 0.125 * log2(e) (log2-domain softmax)
  const float qscale = 0.125f * 1.44269504f;
  bf16x8v qf[2][2];
#pragma unroll
  for (int mi = 0; mi < 2; mi++)
#pragma unroll
    for (int ks = 0; ks < 2; ks++) {
      bf16x8v q = *(const bf16x8v*)&Qb[(wq0 + mi * 16 + lmod) * 64 + ks * 32 + lgrp * 8];
#pragma unroll
      for (int j = 0; j < 8; j++) q[j] = (__bf16)((float)q[j] * qscale);
      qf[mi][ks] = q;
    }

  float m_run[2][4], l_run[2][4];
  f32x4 oacc[2][4];
#pragma unroll
  for (int mi = 0; mi < 2; mi++)
#pragma unroll
    for (int r = 0; r < 4; r++) {
      m_run[mi][r] = -INFINITY;
      l_run[mi][r] = 0.f;
    }
#pragma unroll
  for (int mi = 0; mi < 2; mi++)
#pragma unroll
    for (int nd = 0; nd < 4; nd++)
#pragma unroll
      for (int r = 0; r < 4; r++) oacc[mi][nd][r] = 0.f;

  for (int kv0 = 0; kv0 < 2048; kv0 += 128) {
#pragma unroll
    for (int i = 0; i < 4; i++) {
      const int s = i * 256 + tid;
      {  // Ks: 128 rows x 8 blocks
        const int r = s >> 3, cb = s & 7;
        async_copy16(&Ks[s * 8], &Kb[(size_t)(kv0 + r) * 64 + (cb ^ (r & 7)) * 8]);
      }
      {  // Vts: 64 rows x 16 blocks
        const int r = s >> 4, cb = s & 15;
        async_copy16(&Vts[s * 8], &Vb[(size_t)r * 2048 + kv0 + (cb ^ (r & 7)) * 8]);
      }
    }
    __syncthreads();

    // S = Q K^T  (per wave: 2x8 tiles of 16x16)
    f32x4 s[2][8];
#pragma unroll
    for (int mi = 0; mi < 2; mi++)
#pragma unroll
      for (int ni = 0; ni < 8; ni++)
#pragma unroll
        for (int r = 0; r < 4; r++) s[mi][ni][r] = 0.f;
#pragma unroll
    for (int ks = 0; ks < 2; ks++) {
      bf16x8v kf[8];
#pragma unroll
      for (int ni = 0; ni < 8; ni++) {
        const int row = ni * 16 + lmod;
        kf[ni] = *(const bf16x8v*)&Ks[row * 64 + ((ks * 4 + lgrp) ^ (row & 7)) * 8];
      }
#pragma unroll
      for (int mi = 0; mi < 2; mi++)
#pragma unroll
        for (int ni = 0; ni < 8; ni++)
          s[mi][ni] = __builtin_amdgcn_mfma_f32_16x16x32_bf16(qf[mi][ks], kf[ni],
                                                              s[mi][ni], 0, 0, 0);
    }

    // online softmax, log2 domain (p = exp2(s - m))
#pragma unroll
    for (int mi = 0; mi < 2; mi++)
#pragma unroll
      for (int r = 0; r < 4; r++) {
        float rmax = s[mi][0][r];
#pragma unroll
        for (int ni = 1; ni < 8; ni++) rmax = fmaxf(rmax, s[mi][ni][r]);
#pragma unroll
        for (int msk = 1; msk < 16; msk <<= 1) rmax = fmaxf(rmax, __shfl_xor(rmax, msk));
        const float mold = m_run[mi][r];
        const float mnew = fmaxf(mold, rmax);
        const float alpha = __builtin_amdgcn_exp2f(mold - mnew);
        float psum = 0.f;
#pragma unroll
        for (int ni = 0; ni < 8; ni++) {
          const float p = __builtin_amdgcn_exp2f(s[mi][ni][r] - mnew);
          psum += p;
          Ps[(wq0 + mi * 16 + lgrp * 4 + r) * 136 + ni * 16 + lmod] = (__bf16)p;
        }
#pragma unroll
        for (int msk = 1; msk < 16; msk <<= 1) psum += __shfl_xor(psum, msk);
        l_run[mi][r] = l_run[mi][r] * alpha + psum;
        m_run[mi][r] = mnew;
#pragma unroll
        for (int nd = 0; nd < 4; nd++) oacc[mi][nd][r] *= alpha;
      }

    // O += P V   (P rows are wave-private: no barrier needed between write & read)
#pragma unroll
    for (int ks = 0; ks < 4; ks++) {
      bf16x8v pf[2], vf[4];
#pragma unroll
      for (int mi = 0; mi < 2; mi++)
        pf[mi] = *(const bf16x8v*)&Ps[(wq0 + mi * 16 + lmod) * 136 + ks * 32 + lgrp * 8];
#pragma unroll
      for (int nd = 0; nd < 4; nd++) {
        const int row = nd * 16 + lmod;
        vf[nd] = *(const bf16x8v*)&Vts[row * 128 + ((ks * 4 + lgrp) ^ (row & 7)) * 8];
      }
#pragma unroll
      for (int mi = 0; mi < 2; mi++)
#pragma unroll
        for (int nd = 0; nd < 4; nd++)
          oacc[mi][nd] = __builtin_amdgcn_mfma_f32_16x16x32_bf16(pf[mi], vf[nd],
                                                                 oacc[mi][nd], 0, 0, 0);
    }
    __syncthreads();  // protect Ks/Vts before next stage
  }

  const int b = y >> 4, h = y & 15;
#pragma unroll
  for (int mi = 0; mi < 2; mi++)
#pragma unroll
    for (int r = 0; r < 4; r++) {
      const float inv = 1.f / l_run[mi][r];
      const int srow = qt * 128 + wq0 + mi * 16 + lgrp * 4 + r;
      const size_t base = ((size_t)(b * 2048 + srow)) * 1024 + h * 64;
#pragma unroll
      for (int nd = 0; nd < 4; nd++)
        O[base + nd * 16 + lmod] = (__bf16)(oacc[mi][nd][r] * inv);
    }
}

extern "C" void kernel_launch(void* const* d_in, const int* in_sizes, int n_in,
                              void* d_out, int out_size, void* d_ws, size_t ws_size,
                              hipStream_t stream) {
  const float* Qin = (const float*)d_in[0];
  const float* Kin = (const float*)d_in[1];
  const float* Vin = (const float*)d_in[2];
  const float* Wq = (const float*)d_in[3];
  const float* Wk = (const float*)d_in[4];
  const float* Wv = (const float*)d_in[5];
  const float* Wo = (const float*)d_in[6];
  float* out = (float*)d_out;

  __bf16* base = (__bf16*)d_ws;
  __bf16* Qbf = base;                    // 8388608
  __bf16* Kbf = base + 8388608;
  __bf16* Vbf = base + 16777216;
  __bf16* Wqb = base + 25165824;         // 1048576 each
  __bf16* Wkb = base + 26214400;
  __bf16* Wvb = base + 27262976;
  __bf16* Wob = base + 28311552;
  __bf16* Qh = base + 29360128;          // [B,H,S,dk]
  __bf16* Kh = base + 37748736;          // [B,H,S,dk]
  __bf16* Vt = base + 46137344;          // [B,H,dk,S]
  __bf16* AO = Qbf;                      // aliases Qbf (dead after gemm1)

  CastArgs ca;
  ca.s[0] = Qin; ca.s[1] = Kin; ca.s[2] = Vin;
  ca.s[3] = Wq;  ca.s[4] = Wk;  ca.s[5] = Wv;  ca.s[6] = Wo;
  ca.d[0] = Qbf; ca.d[1] = Kbf; ca.d[2] = Vbf;
  ca.d[3] = Wqb; ca.d[4] = Wkb; ca.d[5] = Wvb; ca.d[6] = Wob;
  cast_kernel<<<dim3(4096, 7), 256, 0, stream>>>(ca);

  const int M = 8192, N = 1024, K = 1024;
  dim3 bb(256);
  gemm_bt<1, __bf16><<<dim3(8, 64), bb, 0, stream>>>(Qbf, Wqb, Qh, M, N, K);
  gemm_bt<1, __bf16><<<dim3(8, 64), bb, 0, stream>>>(Kbf, Wkb, Kh, M, N, K);
  // V^T: swap operands -> Vt[n][s] = sum_k Wv[n][k] * Vin[s][k]  (M=1024, N=8192)
  gemm_bt<3, __bf16><<<dim3(64, 8), bb, 0, stream>>>(Wvb, Vbf, Vt, 1024, 8192, K);
  attn_kernel<<<dim3(16, 64), bb, 0, stream>>>(Qh, Kh, Vt, AO);
  gemm_bt<0, float><<<dim3(8, 64), bb, 0, stream>>>(AO, Wob, out, M, N, K);
}